// Round 1
// baseline (203.557 us; speedup 1.0000x reference)
//
#include <hip/hip_runtime.h>
#include <math.h>

#define B_N   32768
#define D_N   128
#define HIST_N 30
#define M_N   15
#define H_N   4
#define CHUNKS 8
#define FWD_BLOCKS (B_N * D_N / (256 * CHUNKS))   // 2048

// ---------------------------------------------------------------------------
// Kernel 1: compute W2 (4x128) and W3 (4x128) from the tiny parameter math.
// W' = a * (U diag(ratio) U^T) W + r * W   with ratio_i = (softplus(sc_i)*S_i + sh_i)/S_i
// where G = W W^T = U diag(S^2) U^T  (4x4 symmetric eigenproblem, f64 Jacobi).
// ---------------------------------------------------------------------------
__global__ void prep_kernel(const float* __restrict__ w1,
                            const float* __restrict__ cw,
                            const float* __restrict__ sscale,
                            const float* __restrict__ sshift,
                            const float* __restrict__ alpha,
                            const float* __restrict__ rscale,
                            float* __restrict__ W2g,
                            float* __restrict__ W3g) {
    const int t = threadIdx.x;            // 0..127 = d
    __shared__ float  sw[M_N];
    __shared__ float  A[H_N][D_N];        // stage0 src (W1_c), stage1 dst (W3)
    __shared__ float  Bm[H_N][D_N];       // stage0 dst (W2),  stage1 src
    __shared__ double Gsh[H_N][H_N];
    __shared__ double Mm[H_N][H_N];

    // softmax(contract_weights)
    if (t == 0) {
        float mx = cw[0];
        for (int m = 1; m < M_N; ++m) mx = fmaxf(mx, cw[m]);
        float s = 0.f;
        for (int m = 0; m < M_N; ++m) { float e = expf(cw[m] - mx); sw[m] = e; s += e; }
        float inv = 1.f / s;
        for (int m = 0; m < M_N; ++m) sw[m] *= inv;
    }
    __syncthreads();

    // W1_c[h][d] = sum_m sw[m] * w1[m,h,d]
    for (int h = 0; h < H_N; ++h) {
        float acc = 0.f;
        for (int m = 0; m < M_N; ++m)
            acc = fmaf(sw[m], w1[(m * H_N + h) * D_N + t], acc);
        A[h][t] = acc;
    }
    __syncthreads();

    const float a = alpha[0], r = rscale[0];

    for (int stage = 0; stage < 2; ++stage) {
        float (*src)[D_N] = (stage == 0) ? A : Bm;
        float (*dst)[D_N] = (stage == 0) ? Bm : A;

        // Gram matrix G = src src^T, 16 threads each do one (i,j)
        if (t < 16) {
            int i = t >> 2, j = t & 3;
            double s = 0.0;
            for (int d = 0; d < D_N; ++d)
                s += (double)src[i][d] * (double)src[j][d];
            Gsh[i][j] = s;
        }
        __syncthreads();

        if (t == 0) {
            double G[4][4], U[4][4];
            for (int i = 0; i < 4; ++i)
                for (int j = 0; j < 4; ++j) { G[i][j] = Gsh[i][j]; U[i][j] = (i == j) ? 1.0 : 0.0; }
            // cyclic Jacobi
            for (int sweep = 0; sweep < 50; ++sweep) {
                double off = 0.0;
                for (int p = 0; p < 4; ++p)
                    for (int q = p + 1; q < 4; ++q) off += G[p][q] * G[p][q];
                if (off < 1e-28) break;
                for (int p = 0; p < 4; ++p)
                    for (int q = p + 1; q < 4; ++q) {
                        double apq = G[p][q];
                        if (fabs(apq) < 1e-300) continue;
                        double theta = (G[q][q] - G[p][p]) / (2.0 * apq);
                        double tt = ((theta >= 0.0) ? 1.0 : -1.0) /
                                    (fabs(theta) + sqrt(theta * theta + 1.0));
                        double c = 1.0 / sqrt(tt * tt + 1.0), sn = tt * c;
                        for (int i = 0; i < 4; ++i) {
                            double gip = G[i][p], giq = G[i][q];
                            G[i][p] = c * gip - sn * giq;
                            G[i][q] = sn * gip + c * giq;
                        }
                        for (int i = 0; i < 4; ++i) {
                            double gpi = G[p][i], gqi = G[q][i];
                            G[p][i] = c * gpi - sn * gqi;
                            G[q][i] = sn * gpi + c * gqi;
                        }
                        for (int i = 0; i < 4; ++i) {
                            double uip = U[i][p], uiq = U[i][q];
                            U[i][p] = c * uip - sn * uiq;
                            U[i][q] = sn * uip + c * uiq;
                        }
                    }
            }
            // sort eigenvalues descending (match SVD's S ordering)
            int ord[4] = {0, 1, 2, 3};
            for (int i = 0; i < 4; ++i)
                for (int j = i + 1; j < 4; ++j)
                    if (G[ord[j]][ord[j]] > G[ord[i]][ord[i]]) { int tmp = ord[i]; ord[i] = ord[j]; ord[j] = tmp; }
            double ratio[4];
            for (int i = 0; i < 4; ++i) {
                double ev = G[ord[i]][ord[i]];
                double S = sqrt(fmax(ev, 0.0));
                double x = (double)sscale[i];
                double sp = (x > 20.0) ? x : log1p(exp(x));       // softplus
                double Snew = sp * S + (double)sshift[i];
                ratio[i] = (S > 1e-300) ? (Snew / S) : sp;
            }
            for (int i = 0; i < 4; ++i)
                for (int j = 0; j < 4; ++j) {
                    double s = 0.0;
                    for (int k = 0; k < 4; ++k)
                        s += U[i][ord[k]] * ratio[k] * U[j][ord[k]];
                    Mm[i][j] = s;
                }
        }
        __syncthreads();

        // dst = a * (Mm @ src) + r * src
        for (int h = 0; h < H_N; ++h) {
            double s = 0.0;
            for (int k = 0; k < H_N; ++k) s += Mm[h][k] * (double)src[k][t];
            dst[h][t] = (float)((double)a * s + (double)r * (double)src[h][t]);
        }
        __syncthreads();
    }

    for (int h = 0; h < H_N; ++h) {
        W2g[h * D_N + t] = Bm[h][t];   // W2[h][d]
        W3g[h * D_N + t] = A[h][t];    // W3[h][d]
    }
}

// ---------------------------------------------------------------------------
// Kernel 2: the streaming bulk. One thread owns a fixed d = tid&127 and
// processes CHUNKS (=8) consecutive b values, so all per-d parameters
// (60 weights + 17 scalars) live in registers; no LDS, no barriers.
// out[b,d] = sum_h relu( relu(h1_h + b1) * W2[h,d] + b2 ) * W3[h,d] + b3[d]
// h1_h = sum_m pa[b,d,15+m] * w1[m,h,d]
// ---------------------------------------------------------------------------
__global__ __launch_bounds__(256) void fwd_kernel(
        const float* __restrict__ pa,
        const float* __restrict__ w1,
        const float* __restrict__ b1,
        const float* __restrict__ b2,
        const float* __restrict__ b3,
        const float* __restrict__ W2g,
        const float* __restrict__ W3g,
        float* __restrict__ out) {
    const int tid = threadIdx.x;
    const int d = tid & 127;

    // hoist per-d parameters into registers (fully static indexing)
    float wv[M_N][H_N];
#pragma unroll
    for (int m = 0; m < M_N; ++m)
#pragma unroll
        for (int h = 0; h < H_N; ++h)
            wv[m][h] = w1[(m * H_N + h) * D_N + d];

    float b1v[H_N], b2v[H_N], w2v[H_N], w3v[H_N];
#pragma unroll
    for (int h = 0; h < H_N; ++h) {
        b1v[h] = b1[h * D_N + d];
        b2v[h] = b2[h * D_N + d];
        w2v[h] = W2g[h * D_N + d];
        w3v[h] = W3g[h * D_N + d];
    }
    const float b3v = b3[d];

    const int base = blockIdx.x * (256 * CHUNKS) + tid;
#pragma unroll
    for (int c = 0; c < CHUNKS; ++c) {
        const int idx = base + c * 256;                 // = b*128 + d (same d)
        const float* ip = pa + (size_t)idx * HIST_N + (HIST_N - M_N);
        float x[M_N];
#pragma unroll
        for (int m = 0; m < M_N; ++m) x[m] = ip[m];

        float h1[H_N] = {0.f, 0.f, 0.f, 0.f};
#pragma unroll
        for (int m = 0; m < M_N; ++m)
#pragma unroll
            for (int h = 0; h < H_N; ++h)
                h1[h] = fmaf(x[m], wv[m][h], h1[h]);

        float acc = b3v;
#pragma unroll
        for (int h = 0; h < H_N; ++h) {
            float v = fmaxf(h1[h] + b1v[h], 0.f);
            float u = fmaxf(fmaf(v, w2v[h], b2v[h]), 0.f);
            acc = fmaf(u, w3v[h], acc);
        }
        out[idx] = acc;
    }
}

extern "C" void kernel_launch(void* const* d_in, const int* in_sizes, int n_in,
                              void* d_out, int out_size, void* d_ws, size_t ws_size,
                              hipStream_t stream) {
    const float* pa = (const float*)d_in[0];   // (B, D, HIST)
    const float* w1 = (const float*)d_in[1];   // (M, H, D)
    const float* b1 = (const float*)d_in[2];   // (1, H, D)
    const float* b2 = (const float*)d_in[3];   // (1, H, D)
    const float* b3 = (const float*)d_in[4];   // (1, D)
    const float* cw = (const float*)d_in[5];   // (M,)
    const float* ss = (const float*)d_in[6];   // (RANK,)
    const float* sh = (const float*)d_in[7];   // (RANK,)
    const float* al = (const float*)d_in[8];   // (1,)
    const float* rs = (const float*)d_in[9];   // (1,)
    float* out = (float*)d_out;                // (B, D) f32

    float* W2g = (float*)d_ws;                 // 4*128 floats
    float* W3g = W2g + H_N * D_N;              // 4*128 floats

    prep_kernel<<<1, 128, 0, stream>>>(w1, cw, ss, sh, al, rs, W2g, W3g);
    fwd_kernel<<<FWD_BLOCKS, 256, 0, stream>>>(pa, w1, b1, b2, b3, W2g, W3g, out);
}